// Round 12
// baseline (218.331 us; speedup 1.0000x reference)
//
#include <hip/hip_runtime.h>

#define Bb 256
#define Nn 240
#define Ee 4338
#define Ff 28
#define Uu 100
#define Kk 128            // U + F
#define AS 136            // LDS A-panel row stride in u16
#define KP 248            // hT/alpha row stride in u16 (496B rows -> uniform LDS banks)

typedef __attribute__((ext_vector_type(8))) short bf16x8;
typedef __attribute__((ext_vector_type(4))) float f32x4;
typedef unsigned short u16;

__device__ __forceinline__ float bf2f(u16 u) {
  union { unsigned int i; float f; } v; v.i = ((unsigned int)u) << 16; return v.f;
}
__device__ __forceinline__ u16 f2bf(float f) {
  union { float ff; unsigned int i; } v; v.ff = f;
  unsigned int x = v.i;
  return (u16)((x + 0x7fffu + ((x >> 16) & 1u)) >> 16);
}
__device__ __forceinline__ void split4(const float4 v, ushort4& h, ushort4& l) {
  u16 h0 = f2bf(v.x), h1 = f2bf(v.y), h2 = f2bf(v.z), h3 = f2bf(v.w);
  h.x = h0; h.y = h1; h.z = h2; h.w = h3;
  l.x = f2bf(v.x - bf2f(h0)); l.y = f2bf(v.y - bf2f(h1));
  l.z = f2bf(v.z - bf2f(h2)); l.w = f2bf(v.w - bf2f(h3));
}

// ---------------------------------------------------------------------------
// k_fused r21: ONE LAUNCH, ONE BLOCK PER SAMPLE (256 blocks, 512 thr, 8 waves,
// ~151 KB LDS, 1 blk/CU).
// vs r20 (139us, MfmaUtil 6.9%, VALUBusy 28%): the two dominant serial
// structures move to the MFMA pipe:
//  (1) attention = dense GEMM: per 32-dst chunk build u8 multiplicity counts
//      (u32-packed LDS atomics; exact for duplicate edges), convert to
//      split-bf16 alpha + denominators, then alpha[32x240] @ hT[240x100] via
//      MFMA (3-op split scheme, same precision class as other GEMMs). CSR
//      build/cslot/per-dst shfl-chains/hbuf gathers DELETED; edges rescanned
//      from L2 per chunk.
//  (2) att-dots folded into the A-GEMM as weight cols 100/101 (Wg^T att_s/d
//      computed once per block) -> phase-A shfl/atomic epilogue deleted;
//      phase A writes hT (transposed split-bf16, stride KP=248).
// Aliases (timeline-safe): alphaL over panel (dead across C's panel use),
// cntW over gch (cnt dead pre-GEMM, gch written post-GEMM). Phase C byte-
// identical to r19/r20 plus a loop-end barrier protecting the aliases.
// ---------------------------------------------------------------------------
__global__ __launch_bounds__(512, 2) void k_fused(
    const float* __restrict__ stt, const float* __restrict__ inp,
    const float* __restrict__ Wg,
    const float* __restrict__ att_s, const float* __restrict__ att_d,
    const int* __restrict__ esrc, const int* __restrict__ edst,
    const float* __restrict__ gbias, const float* __restrict__ b1,
    const float* __restrict__ Wru, const float* __restrict__ bru,
    const float* __restrict__ Wc, const float* __restrict__ bc,
    float* __restrict__ out) {
  __shared__ __align__(16) char smem[154752];
  u16*      hTH    = (u16*)(smem);                 // 49,600 : h^T hi [100][KP]
  u16*      hTL    = (u16*)(smem + 49600);         // 49,600 : h^T lo
  u16*      panel  = (u16*)(smem + 99200);         // 17,408 : ahL|alL (alias alphaL)
  u16*      ahL    = panel;
  u16*      alL    = panel + 32 * AS;
  u16*      alphaL = panel;                        // alias: B-GEMM A-operand lo
  float*    gch    = (float*)(smem + 116608);      // 12,800 : gstate chunk (alias cntW)
  unsigned* cntW   = (unsigned*)(smem + 116608);   //  7,936 : u8x4 counts [32][62]
  u16*      alphaH = (u16*)(smem + 129408);        // 15,872 : alpha hi [32][KP]
  u16*      ugQ    = (u16*)(smem + 145280);        //  6,400 : u-gate fixpt
  float*    asrcL  = (float*)(smem + 151680);      //    960
  float*    adstL  = (float*)(smem + 152640);      //    960
  float*    denC   = (float*)(smem + 153600);      //    128 : 1/den per chunk-dst
  float*    w_asL  = (float*)(smem + 153728);      //    512 : Wg^T att_s
  float*    w_adL  = (float*)(smem + 154240);      //    512 : Wg^T att_d

  int tid = threadIdx.x;
  int b = blockIdx.x;
  const size_t sbase = (size_t)b * Nn * Uu;
  const size_t ibase = (size_t)b * Nn * Ff;

  int w = tid >> 6, l = tid & 63, l15 = l & 15, q = l >> 4;
  int cw = w * 16 + l15;               // this wave's output column (tile = w)

  f32x4 zero = {0.f, 0.f, 0.f, 0.f};
  bf16x8 z8 = {0, 0, 0, 0, 0, 0, 0, 0};

  // staging helper: rows [c0, c0+rowsn) of [st|xi] -> ahL/alL split-bf16
  auto stageChunk = [&](int c0, int rowsn, int base, int stride) {
    for (int j = base; j < rowsn * 32; j += stride) {
      int r = j >> 5, g = j & 31;
      float4 v = (g < 25)
          ? *(const float4*)(stt + sbase + (size_t)(c0 + r) * Uu + g * 4)
          : *(const float4*)(inp + ibase + (size_t)(c0 + r) * Ff + (g - 25) * 4);
      ushort4 hh, lo;
      split4(v, hh, lo);
      *(ushort4*)(ahL + r * AS + g * 4) = hh;
      *(ushort4*)(alL + r * AS + g * 4) = lo;
    }
  };

  // ---- init: w_as/w_ad (thr<256) || stage chunk 0 (thr>=256) ----
  if (tid < 256) {
    int k = tid & 127;
    const float* av = (tid < 128) ? att_s : att_d;
    float acc = 0.f;
    for (int c = 0; c < Uu; ++c) acc += Wg[c * Kk + k] * av[c];
    ((tid < 128) ? w_asL : w_adL)[k] = acc;
  } else {
    stageChunk(0, 32, tid - 256, 256);
  }
  __syncthreads();

  // ================= phase A: h = x @ [Wg | w_as | w_ad]^T =================
  {
    bf16x8 wh[4], wl[4];
#pragma unroll
    for (int s = 0; s < 4; ++s) {
#pragma unroll
      for (int j = 0; j < 8; ++j) {
        int kp = s * 32 + q * 8 + j;
        float v = (cw < Uu) ? Wg[cw * Kk + kp]
                : (cw == Uu) ? w_asL[kp]
                : (cw == Uu + 1) ? w_adL[kp] : 0.f;
        u16 hh = f2bf(v);
        wh[s][j] = (short)hh;
        wl[s][j] = (short)f2bf(v - bf2f(hh));
      }
    }

    for (int ch0 = 0; ch0 < Nn; ch0 += 32) {
      int rows = Nn - ch0; if (rows > 32) rows = 32;
      int nrt = rows >> 4;
      f32x4 acc[2]; acc[0] = zero; acc[1] = zero;
#pragma unroll
      for (int rt = 0; rt < 2; ++rt) if (rt < nrt) {
#pragma unroll
        for (int s = 0; s < 4; ++s) {
          bf16x8 a = *(const bf16x8*)(ahL + (rt * 16 + l15) * AS + s * 32 + q * 8);
          bf16x8 bb = *(const bf16x8*)(alL + (rt * 16 + l15) * AS + s * 32 + q * 8);
          acc[rt] = __builtin_amdgcn_mfma_f32_16x16x32_bf16(a, wh[s], acc[rt], 0, 0, 0);
          acc[rt] = __builtin_amdgcn_mfma_f32_16x16x32_bf16(bb, wh[s], acc[rt], 0, 0, 0);
          acc[rt] = __builtin_amdgcn_mfma_f32_16x16x32_bf16(a, wl[s], acc[rt], 0, 0, 0);
        }
      }
      // epilogue: transposed split-bf16 h + att-dot columns (no shfl/atomics)
#pragma unroll
      for (int rt = 0; rt < 2; ++rt) if (rt < nrt) {
#pragma unroll
        for (int i = 0; i < 4; ++i) {
          float v = acc[rt][i];
          int krow = ch0 + rt * 16 + q * 4 + i;
          if (cw < Uu) {
            u16 hh = f2bf(v);
            hTH[cw * KP + krow] = hh;
            hTL[cw * KP + krow] = f2bf(v - bf2f(hh));
          } else if (cw == Uu) {
            asrcL[krow] = v;
          } else if (cw == Uu + 1) {
            adstL[krow] = v;
          }
        }
      }
      __syncthreads();                 // MFMA reads of panel done
      int nx = ch0 + 32;
      if (nx < Nn) {
        int rowsn = Nn - nx; if (rowsn > 32) rowsn = 32;
        stageChunk(nx, rowsn, tid, 512);
      }
      __syncthreads();                 // next chunk staged
    }
  }

  // ---- GRU weight fragments: in-register fp32 gather + convert, held ----
  bf16x8 r0h[4], r0l[4], r1h[4], r1l[4], cch[4], ccl[4];
  int cw1 = 128 + cw;                  // ru pass-1 column
#pragma unroll
  for (int s = 0; s < 4; ++s) {
    int kb = s * 32 + q * 8;
#pragma unroll
    for (int j = 0; j < 8; ++j) {
      int kp = kb + j;
      int k = (kp < Uu) ? (kp + Ff) : (kp - Uu);
      float v0 = Wru[k * (2 * Uu) + cw];                       // cw<128<200
      u16 h0 = f2bf(v0);
      r0h[s][j] = (short)h0; r0l[s][j] = (short)f2bf(v0 - bf2f(h0));
      float v1 = (cw1 < 2 * Uu) ? Wru[k * (2 * Uu) + cw1] : 0.f;
      u16 h1 = f2bf(v1);
      r1h[s][j] = (short)h1; r1l[s][j] = (short)f2bf(v1 - bf2f(h1));
      float v2 = (cw < Uu) ? Wc[k * Uu + cw] : 0.f;
      u16 h2 = f2bf(v2);
      cch[s][j] = (short)h2; ccl[s][j] = (short)f2bf(v2 - bf2f(h2));
    }
  }
  float bru0 = bru[cw];
  float bru1 = (cw1 < 2 * Uu) ? bru[cw1] : 0.f;
  float bcv = (cw < Uu) ? bc[cw] : 0.f;
  // attention-GEMM epilogue constants (pass 0/1 columns of this wave)
  int n0 = (w >> 1) * 16 + l15;
  int n1 = (4 + (w >> 1)) * 16 + l15;
  float gb0 = (n0 < Uu) ? gbias[n0] + b1[n0] : 0.f;
  float gb1 = (n1 < Uu) ? gbias[n1] + b1[n1] : 0.f;

  // ============ phase B+C per 32-row chunk: attention-GEMM then GRU ========
  for (int ch0 = 0; ch0 < Nn; ch0 += 32) {
    int rows = Nn - ch0; if (rows > 32) rows = 32;
    int nrt = rows >> 4;

    // ---- B1: zero counts (cntW aliases gch; gch dead since prev C) ----
    for (int i = tid; i < 32 * 62; i += 512) cntW[i] = 0;
    __syncthreads();
    // ---- B2: edge multiplicity histogram (+ self-loops) ----
    for (int e = tid; e < Ee; e += 512) {
      int d = edst[e];
      unsigned r = (unsigned)(d - ch0);
      if (r < 32u) {
        int s = esrc[e];
        atomicAdd(&cntW[r * 62 + (s >> 2)], 1u << (8 * (s & 3)));
      }
    }
    if (tid < rows) {
      int n = ch0 + tid;
      atomicAdd(&cntW[tid * 62 + (n >> 2)], 1u << (8 * (n & 3)));
    }
    __syncthreads();
    // ---- B3: counts -> split-bf16 alpha + 1/den ----
    {
      int d = tid >> 4, j = tid & 15;
      int gd = ch0 + d;
      float dsum = 0.f;
      if (d < rows) {
        float ad = adstL[gd];
        for (int wi = j; wi < 62; wi += 16) {
          unsigned c4 = cntW[d * 62 + wi];
          ushort4 vh = {0, 0, 0, 0}, vl = {0, 0, 0, 0};
          if (c4) {
#pragma unroll
            for (int bb = 0; bb < 4; ++bb) {
              unsigned c = (c4 >> (8 * bb)) & 0xffu;
              if (c) {
                int s = wi * 4 + bb;
                float sc = asrcL[s] + ad;
                sc = (sc > 0.f) ? sc : 0.2f * sc;
                float we = __expf(sc) * (float)c;
                dsum += we;
                u16 hh = f2bf(we);
                ((u16*)&vh)[bb] = hh;
                ((u16*)&vl)[bb] = f2bf(we - bf2f(hh));
              }
            }
          }
          *(ushort4*)(alphaH + d * KP + wi * 4) = vh;
          *(ushort4*)(alphaL + d * KP + wi * 4) = vl;
        }
      }
      dsum += __shfl_xor(dsum, 1, 16);
      dsum += __shfl_xor(dsum, 2, 16);
      dsum += __shfl_xor(dsum, 4, 16);
      dsum += __shfl_xor(dsum, 8, 16);
      if (j == 0 && d < rows) denC[d] = 1.f / dsum;
    }
    __syncthreads();
    // ---- B4: agg = alpha @ hT via MFMA (2 passes over 14 output tiles) ----
#pragma unroll
    for (int p = 0; p < 2; ++p) {
      int mh = w & 1, nt = p * 4 + (w >> 1);
      if (nt > 6 || mh * 16 >= rows) continue;
      int nn = p ? n1 : n0;            // = nt*16 + l15
      bool bv = (nn < Uu);
      int arow = (mh * 16 + l15) * KP;
      int brow = nn * KP;
      f32x4 acc = zero;
#pragma unroll
      for (int s = 0; s < 8; ++s) {
        int ko = s * 32 + q * 8;
        bool kv = (s < 7) || (q < 2);  // mask k>=240 (in-register zeros)
        bf16x8 aH = kv ? *(const bf16x8*)(alphaH + arow + ko) : z8;
        bf16x8 aL = kv ? *(const bf16x8*)(alphaL + arow + ko) : z8;
        bf16x8 bH = (kv && bv) ? *(const bf16x8*)(hTH + brow + ko) : z8;
        bf16x8 bL = (kv && bv) ? *(const bf16x8*)(hTL + brow + ko) : z8;
        acc = __builtin_amdgcn_mfma_f32_16x16x32_bf16(aH, bH, acc, 0, 0, 0);
        acc = __builtin_amdgcn_mfma_f32_16x16x32_bf16(aL, bH, acc, 0, 0, 0);
        acc = __builtin_amdgcn_mfma_f32_16x16x32_bf16(aH, bL, acc, 0, 0, 0);
      }
      if (bv) {
        float gb = p ? gb1 : gb0;
#pragma unroll
        for (int i = 0; i < 4; ++i) {
          int m = mh * 16 + q * 4 + i;
          gch[m * Uu + nn] = acc[i] * denC[m] + gb;
        }
      }
    }
    __syncthreads();   // gch complete; alpha (panel alias) dead

    // ---- C: GRU for rows [ch0, ch0+rows) (unchanged from r19/r20) ----
    for (int j = tid; j < rows * 32; j += 512) {
      int r = j >> 5, g = j & 31;
      float4 v = (g < 25)
          ? *(const float4*)(gch + r * Uu + g * 4)
          : *(const float4*)(inp + ibase + (size_t)(ch0 + r) * Ff + (g - 25) * 4);
      ushort4 hh, lo;
      split4(v, hh, lo);
      *(ushort4*)(ahL + r * AS + g * 4) = hh;
      *(ushort4*)(alL + r * AS + g * 4) = lo;
    }
    float sv[2][4];
#pragma unroll
    for (int rt = 0; rt < 2; ++rt) if (rt < nrt) {
#pragma unroll
      for (int i = 0; i < 4; ++i) {
        int row = rt * 16 + q * 4 + i;
        sv[rt][i] = (cw < Uu) ? gch[row * Uu + cw] : 0.f;
      }
    }
    __syncthreads();   // staging + sv reads of gch done

    float pr[2][4];
    // ru pass 0: cols cw -> r-gate (c<100) + u-gate (100..127)
    {
      f32x4 acc[2]; acc[0] = zero; acc[1] = zero;
#pragma unroll
      for (int rt = 0; rt < 2; ++rt) if (rt < nrt) {
#pragma unroll
        for (int s = 0; s < 4; ++s) {
          bf16x8 a = *(const bf16x8*)(ahL + (rt * 16 + l15) * AS + s * 32 + q * 8);
          bf16x8 bb = *(const bf16x8*)(alL + (rt * 16 + l15) * AS + s * 32 + q * 8);
          acc[rt] = __builtin_amdgcn_mfma_f32_16x16x32_bf16(a, r0h[s], acc[rt], 0, 0, 0);
          acc[rt] = __builtin_amdgcn_mfma_f32_16x16x32_bf16(bb, r0h[s], acc[rt], 0, 0, 0);
          acc[rt] = __builtin_amdgcn_mfma_f32_16x16x32_bf16(a, r0l[s], acc[rt], 0, 0, 0);
        }
      }
#pragma unroll
      for (int rt = 0; rt < 2; ++rt) if (rt < nrt) {
#pragma unroll
        for (int i = 0; i < 4; ++i) {
          int row = rt * 16 + q * 4 + i;
          float y = acc[rt][i] + bru0;
          float g = 1.f / (1.f + __expf(-y));
          if (cw < Uu) pr[rt][i] = g * sv[rt][i];
          else ugQ[row * Uu + (cw - Uu)] = (u16)(g * 65535.f + 0.5f);
        }
      }
    }
    // ru pass 1: cols cw1 in [128,256) -> u-gate (128..199)
    {
      f32x4 acc[2]; acc[0] = zero; acc[1] = zero;
#pragma unroll
      for (int rt = 0; rt < 2; ++rt) if (rt < nrt) {
#pragma unroll
        for (int s = 0; s < 4; ++s) {
          bf16x8 a = *(const bf16x8*)(ahL + (rt * 16 + l15) * AS + s * 32 + q * 8);
          bf16x8 bb = *(const bf16x8*)(alL + (rt * 16 + l15) * AS + s * 32 + q * 8);
          acc[rt] = __builtin_amdgcn_mfma_f32_16x16x32_bf16(a, r1h[s], acc[rt], 0, 0, 0);
          acc[rt] = __builtin_amdgcn_mfma_f32_16x16x32_bf16(bb, r1h[s], acc[rt], 0, 0, 0);
          acc[rt] = __builtin_amdgcn_mfma_f32_16x16x32_bf16(a, r1l[s], acc[rt], 0, 0, 0);
        }
      }
#pragma unroll
      for (int rt = 0; rt < 2; ++rt) if (rt < nrt) {
#pragma unroll
        for (int i = 0; i < 4; ++i) {
          int row = rt * 16 + q * 4 + i;
          float y = acc[rt][i] + bru1;
          float g = 1.f / (1.f + __expf(-y));
          if (cw1 < 2 * Uu) ugQ[row * Uu + (cw1 - Uu)] = (u16)(g * 65535.f + 0.5f);
        }
      }
    }
    __syncthreads();   // all ru LDS reads + ugQ writes complete

    // substitute r*st into A-panel cols < 100
#pragma unroll
    for (int rt = 0; rt < 2; ++rt) if (rt < nrt) {
#pragma unroll
      for (int i = 0; i < 4; ++i) {
        int row = rt * 16 + q * 4 + i;
        if (cw < Uu) {
          float p = pr[rt][i];
          u16 hh = f2bf(p);
          ahL[row * AS + cw] = hh;
          alL[row * AS + cw] = f2bf(p - bf2f(hh));
        }
      }
    }
    __syncthreads();   // cat2 = [r*st | xi] ready

    // c GEMM + blend, cols cw
    {
      f32x4 acc[2]; acc[0] = zero; acc[1] = zero;
#pragma unroll
      for (int rt = 0; rt < 2; ++rt) if (rt < nrt) {
#pragma unroll
        for (int s = 0; s < 4; ++s) {
          bf16x8 a = *(const bf16x8*)(ahL + (rt * 16 + l15) * AS + s * 32 + q * 8);
          bf16x8 bb = *(const bf16x8*)(alL + (rt * 16 + l15) * AS + s * 32 + q * 8);
          acc[rt] = __builtin_amdgcn_mfma_f32_16x16x32_bf16(a, cch[s], acc[rt], 0, 0, 0);
          acc[rt] = __builtin_amdgcn_mfma_f32_16x16x32_bf16(bb, cch[s], acc[rt], 0, 0, 0);
          acc[rt] = __builtin_amdgcn_mfma_f32_16x16x32_bf16(a, ccl[s], acc[rt], 0, 0, 0);
        }
      }
#pragma unroll
      for (int rt = 0; rt < 2; ++rt) if (rt < nrt) {
#pragma unroll
        for (int i = 0; i < 4; ++i) {
          int row = rt * 16 + q * 4 + i;
          if (cw < Uu) {
            float y = acc[rt][i] + bcv;
            float cv = 1.f - 2.f / (__expf(2.f * y) + 1.f);
            float u = (float)ugQ[row * Uu + cw] * (1.f / 65535.f);
            out[sbase + (size_t)(ch0 + row) * Uu + cw] = u * sv[rt][i] + (1.f - u) * cv;
          }
        }
      }
    }
    __syncthreads();   // loop-end: protect panel (alphaL) + gch (cntW) aliases
  }
}

// ---------------------------------------------------------------------------
extern "C" void kernel_launch(void* const* d_in, const int* in_sizes, int n_in,
                              void* d_out, int out_size, void* d_ws, size_t ws_size,
                              hipStream_t stream) {
  const float* inp   = (const float*)d_in[0];
  const float* stt   = (const float*)d_in[1];
  const int*   esrc  = (const int*)d_in[2];
  const int*   edst  = (const int*)d_in[3];
  const float* Wg    = (const float*)d_in[4];
  const float* att_s = (const float*)d_in[5];
  const float* att_d = (const float*)d_in[6];
  const float* gbias = (const float*)d_in[7];
  const float* b1    = (const float*)d_in[8];
  const float* Wru   = (const float*)d_in[9];
  const float* bru   = (const float*)d_in[10];
  const float* Wc    = (const float*)d_in[11];
  const float* bc    = (const float*)d_in[12];
  float* out = (float*)d_out;

  k_fused<<<Bb, 512, 0, stream>>>(stt, inp, Wg, att_s, att_d, esrc, edst,
                                  gbias, b1, Wru, bru, Wc, bc, out);
}

// Round 13
// 213.696 us; speedup vs baseline: 1.0217x; 1.0217x over previous
//
#include <hip/hip_runtime.h>

#define Bb 256
#define Nn 240
#define Ee 4338
#define Ff 28
#define Uu 100
#define Kk 128            // U + F
#define AS 136            // LDS A-panel row stride in u16
#define KP 248            // hT/alpha row stride in u16 (496B rows)

typedef __attribute__((ext_vector_type(8))) short bf16x8;
typedef __attribute__((ext_vector_type(4))) float f32x4;
typedef unsigned short u16;

__device__ __forceinline__ float bf2f(u16 u) {
  union { unsigned int i; float f; } v; v.i = ((unsigned int)u) << 16; return v.f;
}
__device__ __forceinline__ u16 f2bf(float f) {
  union { float ff; unsigned int i; } v; v.ff = f;
  unsigned int x = v.i;
  return (u16)((x + 0x7fffu + ((x >> 16) & 1u)) >> 16);
}
__device__ __forceinline__ void split4(const float4 v, ushort4& h, ushort4& l) {
  u16 h0 = f2bf(v.x), h1 = f2bf(v.y), h2 = f2bf(v.z), h3 = f2bf(v.w);
  h.x = h0; h.y = h1; h.z = h2; h.w = h3;
  l.x = f2bf(v.x - bf2f(h0)); l.y = f2bf(v.y - bf2f(h1));
  l.z = f2bf(v.z - bf2f(h2)); l.w = f2bf(v.w - bf2f(h3));
}

// ---------------------------------------------------------------------------
// k_fused r22: ONE LAUNCH, ONE BLOCK PER SAMPLE (256 blocks, 512 thr, 8 waves,
// ~151 KB LDS, 1 blk/CU).
// vs r21 (137us): same math, shorter barrier-fenced serial chain.
//  (1) edges held in 5 packed u32 REGISTERS per thread (u8 d,s fields; loaded
//      once at init) -> per-chunk global edge rescan DELETED.
//  (2) multiplicity counts live IN alphaH (u32-packed u16 pairs, [32][124]
//      exactly overlays [32][KP] u16); B3 converts in place. cnt/gch alias
//      gone.
//  (3) B1 (zero) folded into C-staging of prev chunk; B2 (hist for chunk k+1)
//      folded into the substitute section of chunk k. Barriers/chunk 8 -> 6.
//  (4) B4 bias reads inlined (frees persistents for the edge regs).
// Count adds are commutative (exact); alpha/GEMM math byte-identical -> same
// absmax. alphaL still aliases panel (dead across C, written only in B3).
// ---------------------------------------------------------------------------
__global__ __launch_bounds__(512, 2) void k_fused(
    const float* __restrict__ stt, const float* __restrict__ inp,
    const float* __restrict__ Wg,
    const float* __restrict__ att_s, const float* __restrict__ att_d,
    const int* __restrict__ esrc, const int* __restrict__ edst,
    const float* __restrict__ gbias, const float* __restrict__ b1,
    const float* __restrict__ Wru, const float* __restrict__ bru,
    const float* __restrict__ Wc, const float* __restrict__ bc,
    float* __restrict__ out) {
  __shared__ __align__(16) char smem[154752];
  u16*      hTH    = (u16*)(smem);                 // 49,600 : h^T hi [100][KP]
  u16*      hTL    = (u16*)(smem + 49600);         // 49,600 : h^T lo
  u16*      panel  = (u16*)(smem + 99200);         // 17,408 : ahL|alL (alias alphaL)
  u16*      ahL    = panel;
  u16*      alL    = panel + 32 * AS;
  u16*      alphaL = panel;                        // alias: B-GEMM A-operand lo
  float*    gch    = (float*)(smem + 116608);      // 12,800 : gstate chunk
  u16*      alphaH = (u16*)(smem + 129408);        // 15,872 : alpha hi / counts
  u16*      ugQ    = (u16*)(smem + 145280);        //  6,400 : u-gate fixpt
  float*    asrcL  = (float*)(smem + 151680);      //    960
  float*    adstL  = (float*)(smem + 152640);      //    960
  float*    denC   = (float*)(smem + 153600);      //    128 : 1/den per chunk-dst
  float*    w_asL  = (float*)(smem + 153728);      //    512 : Wg^T att_s
  float*    w_adL  = (float*)(smem + 154240);      //    512 : Wg^T att_d

  int tid = threadIdx.x;
  int b = blockIdx.x;
  const size_t sbase = (size_t)b * Nn * Uu;
  const size_t ibase = (size_t)b * Nn * Ff;

  int w = tid >> 6, l = tid & 63, l15 = l & 15, q = l >> 4;
  int cw = w * 16 + l15;               // this wave's output column (tile = w)

  f32x4 zero = {0.f, 0.f, 0.f, 0.f};
  bf16x8 z8 = {0, 0, 0, 0, 0, 0, 0, 0};

  // staging helper: rows [c0, c0+rowsn) of [st|xi] -> ahL/alL split-bf16
  auto stageChunk = [&](int c0, int rowsn, int base, int stride) {
    for (int j = base; j < rowsn * 32; j += stride) {
      int r = j >> 5, g = j & 31;
      float4 v = (g < 25)
          ? *(const float4*)(stt + sbase + (size_t)(c0 + r) * Uu + g * 4)
          : *(const float4*)(inp + ibase + (size_t)(c0 + r) * Ff + (g - 25) * 4);
      ushort4 hh, lo;
      split4(v, hh, lo);
      *(ushort4*)(ahL + r * AS + g * 4) = hh;
      *(ushort4*)(alL + r * AS + g * 4) = lo;
    }
  };

  // histogram for chunk [c0, c0+rowsn) from register-held packed edges
  auto histChunk = [&](int c0, int rowsn, unsigned* epk) {
    unsigned* cbase = (unsigned*)alphaH;           // [32][124] u32 (2 u16 cnts)
#pragma unroll
    for (int k = 0; k < 5; ++k) {
      unsigned p = epk[k];
      {
        unsigned d = p & 0xFFu, s = (p >> 8) & 0xFFu;
        unsigned r = d - (unsigned)c0;
        if (r < (unsigned)rowsn)
          atomicAdd(&cbase[r * 124 + (s >> 1)], 1u << (16 * (s & 1)));
      }
      {
        unsigned d = (p >> 16) & 0xFFu, s = p >> 24;
        unsigned r = d - (unsigned)c0;
        if (r < (unsigned)rowsn)
          atomicAdd(&cbase[r * 124 + (s >> 1)], 1u << (16 * (s & 1)));
      }
    }
    if (tid < rowsn) {                 // self-loop
      int n = c0 + tid;
      atomicAdd(&cbase[tid * 124 + (n >> 1)], 1u << (16 * (n & 1)));
    }
  };

  // ---- init: edges->regs, zero counts, w_as/w_ad || stage chunk 0 ----
  unsigned epk[5];
#pragma unroll
  for (int k = 0; k < 5; ++k) {
    int e0 = tid + (2 * k) * 512, e1 = tid + (2 * k + 1) * 512;
    unsigned d0 = 255u, s0 = 255u, d1 = 255u, s1 = 255u;
    if (e0 < Ee) { d0 = (unsigned)edst[e0]; s0 = (unsigned)esrc[e0]; }
    if (e1 < Ee) { d1 = (unsigned)edst[e1]; s1 = (unsigned)esrc[e1]; }
    epk[k] = d0 | (s0 << 8) | (d1 << 16) | (s1 << 24);
  }
  {
    unsigned* cz = (unsigned*)alphaH;
    for (int i = tid; i < 32 * 124; i += 512) cz[i] = 0;
  }
  if (tid < 256) {
    int k = tid & 127;
    const float* av = (tid < 128) ? att_s : att_d;
    float acc = 0.f;
    for (int c = 0; c < Uu; ++c) acc += Wg[c * Kk + k] * av[c];
    ((tid < 128) ? w_asL : w_adL)[k] = acc;
  } else {
    stageChunk(0, 32, tid - 256, 256);
  }
  __syncthreads();

  // ================= phase A: h = x @ [Wg | w_as | w_ad]^T =================
  {
    bf16x8 wh[4], wl[4];
#pragma unroll
    for (int s = 0; s < 4; ++s) {
#pragma unroll
      for (int j = 0; j < 8; ++j) {
        int kp = s * 32 + q * 8 + j;
        float v = (cw < Uu) ? Wg[cw * Kk + kp]
                : (cw == Uu) ? w_asL[kp]
                : (cw == Uu + 1) ? w_adL[kp] : 0.f;
        u16 hh = f2bf(v);
        wh[s][j] = (short)hh;
        wl[s][j] = (short)f2bf(v - bf2f(hh));
      }
    }

    for (int ch0 = 0; ch0 < Nn; ch0 += 32) {
      int rows = Nn - ch0; if (rows > 32) rows = 32;
      int nrt = rows >> 4;
      f32x4 acc[2]; acc[0] = zero; acc[1] = zero;
#pragma unroll
      for (int rt = 0; rt < 2; ++rt) if (rt < nrt) {
#pragma unroll
        for (int s = 0; s < 4; ++s) {
          bf16x8 a = *(const bf16x8*)(ahL + (rt * 16 + l15) * AS + s * 32 + q * 8);
          bf16x8 bb = *(const bf16x8*)(alL + (rt * 16 + l15) * AS + s * 32 + q * 8);
          acc[rt] = __builtin_amdgcn_mfma_f32_16x16x32_bf16(a, wh[s], acc[rt], 0, 0, 0);
          acc[rt] = __builtin_amdgcn_mfma_f32_16x16x32_bf16(bb, wh[s], acc[rt], 0, 0, 0);
          acc[rt] = __builtin_amdgcn_mfma_f32_16x16x32_bf16(a, wl[s], acc[rt], 0, 0, 0);
        }
      }
      // epilogue: transposed split-bf16 h + att-dot columns
#pragma unroll
      for (int rt = 0; rt < 2; ++rt) if (rt < nrt) {
#pragma unroll
        for (int i = 0; i < 4; ++i) {
          float v = acc[rt][i];
          int krow = ch0 + rt * 16 + q * 4 + i;
          if (cw < Uu) {
            u16 hh = f2bf(v);
            hTH[cw * KP + krow] = hh;
            hTL[cw * KP + krow] = f2bf(v - bf2f(hh));
          } else if (cw == Uu) {
            asrcL[krow] = v;
          } else if (cw == Uu + 1) {
            adstL[krow] = v;
          }
        }
      }
      __syncthreads();                 // MFMA reads of panel done
      int nx = ch0 + 32;
      if (nx < Nn) {
        int rowsn = Nn - nx; if (rowsn > 32) rowsn = 32;
        stageChunk(nx, rowsn, tid, 512);
      }
      __syncthreads();                 // next chunk staged
    }
  }

  // ---- GRU weight fragments (in-reg gather) + hist chunk 0 (overlapped) ----
  histChunk(0, 32, epk);
  bf16x8 r0h[4], r0l[4], r1h[4], r1l[4], cch[4], ccl[4];
  int cw1 = 128 + cw;                  // ru pass-1 column
#pragma unroll
  for (int s = 0; s < 4; ++s) {
    int kb = s * 32 + q * 8;
#pragma unroll
    for (int j = 0; j < 8; ++j) {
      int kp = kb + j;
      int k = (kp < Uu) ? (kp + Ff) : (kp - Uu);
      float v0 = Wru[k * (2 * Uu) + cw];                       // cw<128<200
      u16 h0 = f2bf(v0);
      r0h[s][j] = (short)h0; r0l[s][j] = (short)f2bf(v0 - bf2f(h0));
      float v1 = (cw1 < 2 * Uu) ? Wru[k * (2 * Uu) + cw1] : 0.f;
      u16 h1 = f2bf(v1);
      r1h[s][j] = (short)h1; r1l[s][j] = (short)f2bf(v1 - bf2f(h1));
      float v2 = (cw < Uu) ? Wc[k * Uu + cw] : 0.f;
      u16 h2 = f2bf(v2);
      cch[s][j] = (short)h2; ccl[s][j] = (short)f2bf(v2 - bf2f(h2));
    }
  }
  float bru0 = bru[cw];
  float bru1 = (cw1 < 2 * Uu) ? bru[cw1] : 0.f;
  float bcv = (cw < Uu) ? bc[cw] : 0.f;
  int n0 = (w >> 1) * 16 + l15;        // attention-GEMM pass-0/1 columns
  int n1 = (4 + (w >> 1)) * 16 + l15;
  __syncthreads();                     // hist(0) complete

  // ============ phase B+C per 32-row chunk ============
  for (int ch0 = 0; ch0 < Nn; ch0 += 32) {
    int rows = Nn - ch0; if (rows > 32) rows = 32;
    int nrt = rows >> 4;
    int nx = ch0 + 32;
    int rows_nx = (nx < Nn) ? ((Nn - nx > 32) ? 32 : (Nn - nx)) : 0;

    // ---- B3: counts (in alphaH) -> split-bf16 alpha (in place) + 1/den ----
    {
      int d = tid >> 4, j = tid & 15;
      float dsum = 0.f;
      if (d < rows) {
        float ad = adstL[ch0 + d];
        unsigned* crow = (unsigned*)(alphaH + d * KP);
        unsigned* lrow = (unsigned*)(alphaL + d * KP);
        for (int wd = j; wd < 120; wd += 16) {
          unsigned c2 = crow[wd];
          unsigned hi2 = 0, lo2 = 0;
          if (c2) {
            unsigned ca = c2 & 0xFFFFu, cb = c2 >> 16;
            if (ca) {
              int s = 2 * wd;
              float sc = asrcL[s] + ad;
              sc = (sc > 0.f) ? sc : 0.2f * sc;
              float we = __expf(sc) * (float)ca;
              dsum += we;
              u16 hh = f2bf(we);
              hi2 |= (unsigned)hh;
              lo2 |= (unsigned)f2bf(we - bf2f(hh));
            }
            if (cb) {
              int s = 2 * wd + 1;
              float sc = asrcL[s] + ad;
              sc = (sc > 0.f) ? sc : 0.2f * sc;
              float we = __expf(sc) * (float)cb;
              dsum += we;
              u16 hh = f2bf(we);
              hi2 |= ((unsigned)hh) << 16;
              lo2 |= ((unsigned)f2bf(we - bf2f(hh))) << 16;
            }
          }
          crow[wd] = hi2;
          lrow[wd] = lo2;
        }
      }
      dsum += __shfl_xor(dsum, 1, 16);
      dsum += __shfl_xor(dsum, 2, 16);
      dsum += __shfl_xor(dsum, 4, 16);
      dsum += __shfl_xor(dsum, 8, 16);
      if (j == 0 && d < rows) denC[d] = 1.f / dsum;
    }
    __syncthreads();

    // ---- B4: agg = alpha @ hT via MFMA ----
#pragma unroll
    for (int p = 0; p < 2; ++p) {
      int mh = w & 1, nt = p * 4 + (w >> 1);
      if (nt > 6 || mh * 16 >= rows) continue;
      int nn = p ? n1 : n0;            // = nt*16 + l15
      bool bv = (nn < Uu);
      int arow = (mh * 16 + l15) * KP;
      int brow = nn * KP;
      f32x4 acc = zero;
#pragma unroll
      for (int s = 0; s < 8; ++s) {
        int ko = s * 32 + q * 8;
        bool kv = (s < 7) || (q < 2);  // mask k>=240
        bf16x8 aH = kv ? *(const bf16x8*)(alphaH + arow + ko) : z8;
        bf16x8 aL = kv ? *(const bf16x8*)(alphaL + arow + ko) : z8;
        bf16x8 bH = (kv && bv) ? *(const bf16x8*)(hTH + brow + ko) : z8;
        bf16x8 bL = (kv && bv) ? *(const bf16x8*)(hTL + brow + ko) : z8;
        acc = __builtin_amdgcn_mfma_f32_16x16x32_bf16(aH, bH, acc, 0, 0, 0);
        acc = __builtin_amdgcn_mfma_f32_16x16x32_bf16(aL, bH, acc, 0, 0, 0);
        acc = __builtin_amdgcn_mfma_f32_16x16x32_bf16(aH, bL, acc, 0, 0, 0);
      }
      if (bv) {
        float gb = gbias[nn] + b1[nn];
#pragma unroll
        for (int i = 0; i < 4; ++i) {
          int m = mh * 16 + q * 4 + i;
          gch[m * Uu + nn] = acc[i] * denC[m] + gb;
        }
      }
    }
    __syncthreads();   // gch complete; alpha dead

    // ---- C stage + sv + zero next chunk's counts ----
    for (int j = tid; j < rows * 32; j += 512) {
      int r = j >> 5, g = j & 31;
      float4 v = (g < 25)
          ? *(const float4*)(gch + r * Uu + g * 4)
          : *(const float4*)(inp + ibase + (size_t)(ch0 + r) * Ff + (g - 25) * 4);
      ushort4 hh, lo;
      split4(v, hh, lo);
      *(ushort4*)(ahL + r * AS + g * 4) = hh;
      *(ushort4*)(alL + r * AS + g * 4) = lo;
    }
    if (rows_nx) {
      unsigned* cz = (unsigned*)alphaH;
      for (int i = tid; i < 32 * 124; i += 512) cz[i] = 0;
    }
    float sv[2][4];
#pragma unroll
    for (int rt = 0; rt < 2; ++rt) if (rt < nrt) {
#pragma unroll
      for (int i = 0; i < 4; ++i) {
        int row = rt * 16 + q * 4 + i;
        sv[rt][i] = (cw < Uu) ? gch[row * Uu + cw] : 0.f;
      }
    }
    __syncthreads();   // staging + sv + zeroing done

    float pr[2][4];
    // ru pass 0: cols cw -> r-gate (c<100) + u-gate (100..127)
    {
      f32x4 acc[2]; acc[0] = zero; acc[1] = zero;
#pragma unroll
      for (int rt = 0; rt < 2; ++rt) if (rt < nrt) {
#pragma unroll
        for (int s = 0; s < 4; ++s) {
          bf16x8 a = *(const bf16x8*)(ahL + (rt * 16 + l15) * AS + s * 32 + q * 8);
          bf16x8 bb = *(const bf16x8*)(alL + (rt * 16 + l15) * AS + s * 32 + q * 8);
          acc[rt] = __builtin_amdgcn_mfma_f32_16x16x32_bf16(a, r0h[s], acc[rt], 0, 0, 0);
          acc[rt] = __builtin_amdgcn_mfma_f32_16x16x32_bf16(bb, r0h[s], acc[rt], 0, 0, 0);
          acc[rt] = __builtin_amdgcn_mfma_f32_16x16x32_bf16(a, r0l[s], acc[rt], 0, 0, 0);
        }
      }
#pragma unroll
      for (int rt = 0; rt < 2; ++rt) if (rt < nrt) {
#pragma unroll
        for (int i = 0; i < 4; ++i) {
          int row = rt * 16 + q * 4 + i;
          float y = acc[rt][i] + bru0;
          float g = 1.f / (1.f + __expf(-y));
          if (cw < Uu) pr[rt][i] = g * sv[rt][i];
          else ugQ[row * Uu + (cw - Uu)] = (u16)(g * 65535.f + 0.5f);
        }
      }
    }
    // ru pass 1: cols cw1 in [128,256) -> u-gate (128..199)
    {
      f32x4 acc[2]; acc[0] = zero; acc[1] = zero;
#pragma unroll
      for (int rt = 0; rt < 2; ++rt) if (rt < nrt) {
#pragma unroll
        for (int s = 0; s < 4; ++s) {
          bf16x8 a = *(const bf16x8*)(ahL + (rt * 16 + l15) * AS + s * 32 + q * 8);
          bf16x8 bb = *(const bf16x8*)(alL + (rt * 16 + l15) * AS + s * 32 + q * 8);
          acc[rt] = __builtin_amdgcn_mfma_f32_16x16x32_bf16(a, r1h[s], acc[rt], 0, 0, 0);
          acc[rt] = __builtin_amdgcn_mfma_f32_16x16x32_bf16(bb, r1h[s], acc[rt], 0, 0, 0);
          acc[rt] = __builtin_amdgcn_mfma_f32_16x16x32_bf16(a, r1l[s], acc[rt], 0, 0, 0);
        }
      }
#pragma unroll
      for (int rt = 0; rt < 2; ++rt) if (rt < nrt) {
#pragma unroll
        for (int i = 0; i < 4; ++i) {
          int row = rt * 16 + q * 4 + i;
          float y = acc[rt][i] + bru1;
          float g = 1.f / (1.f + __expf(-y));
          if (cw1 < 2 * Uu) ugQ[row * Uu + (cw1 - Uu)] = (u16)(g * 65535.f + 0.5f);
        }
      }
    }
    __syncthreads();   // all ru LDS reads + ugQ writes complete

    // substitute r*st into A-panel cols < 100, + histogram next chunk
#pragma unroll
    for (int rt = 0; rt < 2; ++rt) if (rt < nrt) {
#pragma unroll
      for (int i = 0; i < 4; ++i) {
        int row = rt * 16 + q * 4 + i;
        if (cw < Uu) {
          float p = pr[rt][i];
          u16 hh = f2bf(p);
          ahL[row * AS + cw] = hh;
          alL[row * AS + cw] = f2bf(p - bf2f(hh));
        }
      }
    }
    if (rows_nx) histChunk(nx, rows_nx, epk);
    __syncthreads();   // cat2 ready + hist(next) complete

    // c GEMM + blend, cols cw
    {
      f32x4 acc[2]; acc[0] = zero; acc[1] = zero;
#pragma unroll
      for (int rt = 0; rt < 2; ++rt) if (rt < nrt) {
#pragma unroll
        for (int s = 0; s < 4; ++s) {
          bf16x8 a = *(const bf16x8*)(ahL + (rt * 16 + l15) * AS + s * 32 + q * 8);
          bf16x8 bb = *(const bf16x8*)(alL + (rt * 16 + l15) * AS + s * 32 + q * 8);
          acc[rt] = __builtin_amdgcn_mfma_f32_16x16x32_bf16(a, cch[s], acc[rt], 0, 0, 0);
          acc[rt] = __builtin_amdgcn_mfma_f32_16x16x32_bf16(bb, cch[s], acc[rt], 0, 0, 0);
          acc[rt] = __builtin_amdgcn_mfma_f32_16x16x32_bf16(a, ccl[s], acc[rt], 0, 0, 0);
        }
      }
#pragma unroll
      for (int rt = 0; rt < 2; ++rt) if (rt < nrt) {
#pragma unroll
        for (int i = 0; i < 4; ++i) {
          int row = rt * 16 + q * 4 + i;
          if (cw < Uu) {
            float y = acc[rt][i] + bcv;
            float cv = 1.f - 2.f / (__expf(2.f * y) + 1.f);
            float u = (float)ugQ[row * Uu + cw] * (1.f / 65535.f);
            out[sbase + (size_t)(ch0 + row) * Uu + cw] = u * sv[rt][i] + (1.f - u) * cv;
          }
        }
      }
    }
    __syncthreads();   // loop-end: protect panel (alphaL alias) for next B3
  }
}

// ---------------------------------------------------------------------------
extern "C" void kernel_launch(void* const* d_in, const int* in_sizes, int n_in,
                              void* d_out, int out_size, void* d_ws, size_t ws_size,
                              hipStream_t stream) {
  const float* inp   = (const float*)d_in[0];
  const float* stt   = (const float*)d_in[1];
  const int*   esrc  = (const int*)d_in[2];
  const int*   edst  = (const int*)d_in[3];
  const float* Wg    = (const float*)d_in[4];
  const float* att_s = (const float*)d_in[5];
  const float* att_d = (const float*)d_in[6];
  const float* gbias = (const float*)d_in[7];
  const float* b1    = (const float*)d_in[8];
  const float* Wru   = (const float*)d_in[9];
  const float* bru   = (const float*)d_in[10];
  const float* Wc    = (const float*)d_in[11];
  const float* bc    = (const float*)d_in[12];
  float* out = (float*)d_out;

  k_fused<<<Bb, 512, 0, stream>>>(stt, inp, Wg, att_s, att_d, esrc, edst,
                                  gbias, b1, Wru, bru, Wc, bc, out);
}